// Round 5
// baseline (75252.753 us; speedup 1.0000x reference)
//
#include <hip/hip_runtime.h>
#include <math.h>

#define T_STEPS 512
#define NL      5

typedef short bf16x8 __attribute__((ext_vector_type(8)));
typedef float f32x4  __attribute__((ext_vector_type(4)));
typedef unsigned long long u64;

// ---- workspace layout (bytes) ----
#define OFF_P     0ull                         // [32768][1024] f32 = 134217728
#define OFF_W     134217728ull                 // 3 planes x 1048576 shorts
#define OFF_R     (OFF_W + 6291456ull)         // 3 planes x 2621440 shorts
#define OFF_WBC   (OFF_R + 15728640ull)        // [1024] f32
#define OFF_RBC   (OFF_WBC + 4096ull)          // [5][1024] f32
#define OFF_H     (OFF_RBC + 20480ull)         // 2 bufs x [4 rg][3 plane][16][512] shorts
#define OFF_FLAGS (OFF_H + 393216ull)          // 1024 u32 (256 WGs x 16B-padded flags)

#define WPLANE 1048576      // shorts per W plane
#define RPLANE 2621440      // shorts per R plane
#define HBUFSTRIDE 98304    // shorts per h buffer  (4 rg x 3 planes x 16 x 512)
#define RGSLICE 24576       // shorts per row-group slice (3 x 16 x 512)

__device__ __forceinline__ unsigned bf_rne(float f) {
    unsigned u = __float_as_uint(f);
    unsigned r = u + 0x7FFFu + ((u >> 16) & 1u);
    return r >> 16;
}
__device__ __forceinline__ float bf_to_f(unsigned bits) {
    return __uint_as_float(bits << 16);
}
// 3-way bf16 split: f = s0 + s1 + s2 + O(2^-27 |f|)
__device__ __forceinline__ void split3(float f, short& s0, short& s1, short& s2) {
    unsigned b0 = bf_rne(f);
    float r1 = f - bf_to_f(b0);
    unsigned b1 = bf_rne(r1);
    float r2 = r1 - bf_to_f(b1);
    unsigned b2 = bf_rne(r2);
    s0 = (short)b0; s1 = (short)b1; s2 = (short)b2;
}
__device__ __forceinline__ float fast_sigmoid(float x) { return 1.0f / (1.0f + __expf(-x)); }
__device__ __forceinline__ float fast_tanh(float x)    { return 2.0f / (1.0f + __expf(-2.0f * x)) - 1.0f; }
// reinterpret two u64 (16B) as a bf16x8 fragment — folds to a bitcast, no memory
__device__ __forceinline__ bf16x8 asbf(u64 lo, u64 hi) {
    u64 q[2] = {lo, hi};
    bf16x8 r;
    __builtin_memcpy(&r, q, 16);
    return r;
}

// ---------------- prep: convert/transpose weights (split-3), zero state ----------------
__global__ void rhn_prep(const float* __restrict__ WHw, const float* __restrict__ WHb,
                         const float* __restrict__ WCw, const float* __restrict__ WCb,
                         const float* __restrict__ RHw, const float* __restrict__ RHb,
                         const float* __restrict__ RCw, const float* __restrict__ RCb,
                         short* __restrict__ Wt, short* __restrict__ Rt,
                         float* __restrict__ wbc, float* __restrict__ rbc,
                         short* __restrict__ hbuf, unsigned* __restrict__ flags)
{
    long long idx = (long long)blockIdx.x * blockDim.x + threadIdx.x;
    if (idx < WPLANE) {            // Wt[n][d] <- W[d][n] combined [H|C]
        int n = (int)(idx >> 10), d = (int)(idx & 1023);
        float v = (n < 512) ? WHw[d * 512 + n] : WCw[d * 512 + (n - 512)];
        short s0, s1, s2; split3(v, s0, s1, s2);
        Wt[idx] = s0; Wt[WPLANE + idx] = s1; Wt[2 * WPLANE + idx] = s2;
        return;
    }
    idx -= WPLANE;
    if (idx < RPLANE) {            // Rt[l][cc][k] <- R[l][k][cc]
        int l = (int)(idx >> 19);
        int rem = (int)(idx & 524287);
        int cc = rem >> 9, k = rem & 511;
        float v = (cc < 512) ? RHw[(l * 512 + k) * 512 + cc]
                             : RCw[(l * 512 + k) * 512 + (cc - 512)];
        short s0, s1, s2; split3(v, s0, s1, s2);
        Rt[idx] = s0; Rt[RPLANE + idx] = s1; Rt[2 * RPLANE + idx] = s2;
        return;
    }
    idx -= RPLANE;
    if (idx < 1024) { wbc[idx] = (idx < 512) ? WHb[idx] : WCb[idx - 512]; return; }
    idx -= 1024;
    if (idx < 5120) {
        int l = (int)(idx >> 10), c = (int)(idx & 1023);
        rbc[idx] = (c < 512) ? RHb[l * 512 + c] : RCb[l * 512 + (c - 512)];
        return;
    }
    idx -= 5120;
    if (idx < 2 * HBUFSTRIDE) { hbuf[idx] = 0; return; }
    idx -= 2 * HBUFSTRIDE;
    if (idx < 1024) { flags[idx] = 0u; return; }
}

// ---------------- projection: P = x @ [W_H | W_C] + bias (split-3, 6 terms) ----------------
__global__ void __launch_bounds__(256) rhn_proj(const float* __restrict__ x,
                                                const short* __restrict__ Wt,
                                                const float* __restrict__ wbc,
                                                float* __restrict__ P)
{
    const int bx = blockIdx.x;          // 0..15  (64-col tiles)
    const int by = blockIdx.y;          // 0..511 (64-row tiles)
    const int tid = threadIdx.x, wave = tid >> 6, lane = tid & 63;
    const int n = lane & 15, quad = lane >> 4;
    const int rowA = by * 64 + wave * 16 + n;    // A-frag row (m = lane&15)
    const float* xrow = x + (long long)rowA * 1024;

    f32x4 acc[4];
#pragma unroll
    for (int nt = 0; nt < 4; ++nt) {
        float b = wbc[bx * 64 + nt * 16 + n];
        acc[nt][0] = b; acc[nt][1] = b; acc[nt][2] = b; acc[nt][3] = b;
    }

    for (int ks = 0; ks < 32; ++ks) {
        const int ko = ks * 32 + quad * 8;
        f32x4 f0 = *(const f32x4*)(xrow + ko);
        f32x4 f1 = *(const f32x4*)(xrow + ko + 4);
        bf16x8 a0, a1, a2;
#pragma unroll
        for (int i = 0; i < 4; ++i) {
            short u0, u1, u2;
            split3(f0[i], u0, u1, u2);
            a0[i] = u0; a1[i] = u1; a2[i] = u2;
            split3(f1[i], u0, u1, u2);
            a0[4 + i] = u0; a1[4 + i] = u1; a2[4 + i] = u2;
        }
#pragma unroll
        for (int nt = 0; nt < 4; ++nt) {
            const long long wi = (long long)(bx * 64 + nt * 16 + n) * 1024 + ko;
            bf16x8 b0 = *(const bf16x8*)(Wt + wi);
            bf16x8 b1 = *(const bf16x8*)(Wt + WPLANE + wi);
            bf16x8 b2 = *(const bf16x8*)(Wt + 2 * WPLANE + wi);
            acc[nt] = __builtin_amdgcn_mfma_f32_16x16x32_bf16(a2, b0, acc[nt], 0, 0, 0);
            acc[nt] = __builtin_amdgcn_mfma_f32_16x16x32_bf16(a1, b1, acc[nt], 0, 0, 0);
            acc[nt] = __builtin_amdgcn_mfma_f32_16x16x32_bf16(a0, b2, acc[nt], 0, 0, 0);
            acc[nt] = __builtin_amdgcn_mfma_f32_16x16x32_bf16(a1, b0, acc[nt], 0, 0, 0);
            acc[nt] = __builtin_amdgcn_mfma_f32_16x16x32_bf16(a0, b1, acc[nt], 0, 0, 0);
            acc[nt] = __builtin_amdgcn_mfma_f32_16x16x32_bf16(a0, b0, acc[nt], 0, 0, 0);
        }
    }
#pragma unroll
    for (int nt = 0; nt < 4; ++nt)
#pragma unroll
        for (int r = 0; r < 4; ++r)
            P[(long long)(by * 64 + wave * 16 + quad * 4 + r) * 1024 + bx * 64 + nt * 16 + n] = acc[nt][r];
}

// ---------------- persistent recurrent kernel ----------------
// 256 WGs = 4 row-groups x 64 col-groups (16 combined cols each; 8 H + 8 C).
// All R weights live in registers (w[5][3][4] bf16x8 = 240 VGPRs/wave, loaded
// once). The 4 waves of a WG K-split the 512-deep dot product (128 each) and
// reduce via LDS. A-fragments are loaded straight from hbuf (no LDS staging).
// Exchange made ARCHITECTURALLY ordered (weights are register-resident, so
// agent acquire/release cache ops no longer cost us a weight cache):
//   writer: h stores -> B2 -> flag store with __ATOMIC_RELEASE (vmcnt drain +
//           writeback ordered before flag visibility)
//   reader: poll flags -> acquire fence (waitcnt + invalidate) -> h loads
__global__ void __launch_bounds__(256, 1) rhn_rec(const float* __restrict__ P,
                                                  const short* __restrict__ Rt,
                                                  const float* __restrict__ rbc,
                                                  short* __restrict__ hbuf,
                                                  unsigned* __restrict__ flags,
                                                  float* __restrict__ out)
{
    __shared__ float2 red[18][64];      // [ (wv-1)*6 + p*2 + rpair ][lane]
    const int wg   = blockIdx.x;        // 0..255
    const int rg   = wg >> 6;           // row-group 0..3
    const int cg   = wg & 63;           // col-group 0..63
    const int tid  = threadIdx.x;
    const int wv   = tid >> 6;          // wave = K-quarter 0..3
    const int lane = tid & 63;
    const int n    = lane & 15;
    const int quad = lane >> 4;
    const bool isH = (n < 8);
    const int jH   = cg * 8 + (n & 7);             // owned H-col (0..511)
    const int ccol = isH ? jH : (512 + jH);        // combined col for B/bias
    const int rowloc = quad * 4;                   // local D-row base (+r)
    const int grow = rg * 16 + rowloc;             // global batch row base (+r)

    // ---- weights resident in registers: w[layer][plane][ks] ----
    bf16x8 w[NL][3][4];
#pragma unroll
    for (int l = 0; l < NL; ++l) {
        const short* bp = Rt + ((l * 1024 + ccol) << 9) + wv * 128 + quad * 8;
#pragma unroll
        for (int p = 0; p < 3; ++p)
#pragma unroll
            for (int ks = 0; ks < 4; ++ks)
                w[l][p][ks] = *(const bf16x8*)(bp + p * RPLANE + ks * 32);
    }
    float rb[NL];
#pragma unroll
    for (int l = 0; l < NL; ++l) rb[l] = rbc[l * 1024 + ccol];

    float hold[4] = {0.f, 0.f, 0.f, 0.f};         // exact f32 hidden (wave0 isH lanes)
    float hn[4];
    float pv[4];                                   // prefetched P rows for next l==0
#pragma unroll
    for (int r = 0; r < 4; ++r) pv[r] = P[(grow + r) * 1024 + ccol];   // t = 0

    float* hidOut = out + 33554432;                // hiddens region [64][1024]
    unsigned* const myflag = flags + (wg << 2);    // 16B-padded per-WG flag
    const unsigned* const gflags = flags + (rg << 8);  // this rg's 64 flags
    const u64* const hb = (const u64*)hbuf;
    // u64 index of this lane's A-frag base within a buffer:
    //   rg slice + row n (*128 u64) + K-quarter + quad sub-offset
    const int abase = rg * (RGSLICE / 4) + n * 128 + wv * 32 + quad * 2;

    unsigned stage = 0;

    auto layer = [&](const bf16x8 (&wl)[3][4], const float rbl,
                     const int lfirst, const int llast,
                     const int t, const int pass, const int step) {
        // ---- A-fragment loads: agent-coherent, straight to registers ----
        const u64* src = hb + (stage & 1u) * (HBUFSTRIDE / 4) + abase;
        u64 va[3][4][2];
#pragma unroll
        for (int p = 0; p < 3; ++p)
#pragma unroll
            for (int ks = 0; ks < 4; ++ks)
#pragma unroll
                for (int h2 = 0; h2 < 2; ++h2)
                    va[p][ks][h2] = __hip_atomic_load(src + p * 2048 + ks * 8 + h2,
                                                      __ATOMIC_RELAXED,
                                                      __HIP_MEMORY_SCOPE_AGENT);

        // ---- partial GEMM over this wave's K-quarter (split-3, 6 terms) ----
        f32x4 acc[3];
#pragma unroll
        for (int r = 0; r < 4; ++r) {
            float s = 0.f;
            if (wv == 0) { s = rbl; if (lfirst) s += pv[r]; }  // seed only once
            acc[0][r] = s; acc[1][r] = 0.f; acc[2][r] = 0.f;
        }
#pragma unroll
        for (int ks = 0; ks < 4; ++ks) {
            bf16x8 a0 = asbf(va[0][ks][0], va[0][ks][1]);
            bf16x8 a1 = asbf(va[1][ks][0], va[1][ks][1]);
            bf16x8 a2 = asbf(va[2][ks][0], va[2][ks][1]);
            acc[0] = __builtin_amdgcn_mfma_f32_16x16x32_bf16(a0, wl[0][ks], acc[0], 0, 0, 0);
            acc[1] = __builtin_amdgcn_mfma_f32_16x16x32_bf16(a1, wl[0][ks], acc[1], 0, 0, 0);
            acc[2] = __builtin_amdgcn_mfma_f32_16x16x32_bf16(a2, wl[0][ks], acc[2], 0, 0, 0);
            acc[0] = __builtin_amdgcn_mfma_f32_16x16x32_bf16(a0, wl[1][ks], acc[0], 0, 0, 0);
            acc[1] = __builtin_amdgcn_mfma_f32_16x16x32_bf16(a1, wl[1][ks], acc[1], 0, 0, 0);
            acc[2] = __builtin_amdgcn_mfma_f32_16x16x32_bf16(a0, wl[2][ks], acc[2], 0, 0, 0);
        }

        // ---- cross-wave K reduction (conflict-free float2 layout) ----
        if (wv != 0) {
            const int rbase = (wv - 1) * 6;
#pragma unroll
            for (int p = 0; p < 3; ++p)
#pragma unroll
                for (int rp = 0; rp < 2; ++rp)
                    red[rbase + p * 2 + rp][lane] =
                        make_float2(acc[p][rp * 2], acc[p][rp * 2 + 1]);
        }
        __syncthreads();    // B1: partials visible to wave 0

        if (wv == 0) {
#pragma unroll
            for (int w2 = 0; w2 < 3; ++w2)
#pragma unroll
                for (int p = 0; p < 3; ++p)
#pragma unroll
                    for (int rp = 0; rp < 2; ++rp) {
                        float2 v2 = red[w2 * 6 + p * 2 + rp][lane];
                        acc[p][rp * 2]     += v2.x;
                        acc[p][rp * 2 + 1] += v2.y;
                    }
            // ---- activation + gate exchange + highway mix ----
#pragma unroll
            for (int r = 0; r < 4; ++r) {
                float pf = (acc[2][r] + acc[1][r]) + acc[0][r];   // small-to-large
                float a  = isH ? fast_tanh(pf) : fast_sigmoid(pf);
                float o  = __shfl_xor(a, 8, 64);
                hn[r] = a * o + hold[r] * (1.0f - o);             // valid on isH lanes
            }
            if (isH) {
                unsigned pk[3][4];
#pragma unroll
                for (int r = 0; r < 4; ++r) {
                    hold[r] = hn[r];
                    short s0, s1, s2; split3(hn[r], s0, s1, s2);
                    pk[0][r] = (unsigned short)s0;
                    pk[1][r] = (unsigned short)s1;
                    pk[2][r] = (unsigned short)s2;
                }
                // pack neighbor col (n^1) into high half -> 4B coherent stores
#pragma unroll
                for (int p2 = 0; p2 < 3; ++p2)
#pragma unroll
                    for (int r = 0; r < 4; ++r) {
                        unsigned nb = __shfl_xor(pk[p2][r], 1, 64);
                        pk[p2][r] |= (nb << 16);
                    }
                if (!(n & 1)) {
                    unsigned* hwU = (unsigned*)hbuf + ((stage & 1u) ^ 1u) * 49152
                                    + rg * 12288 + (jH >> 1);
#pragma unroll
                    for (int p2 = 0; p2 < 3; ++p2)
#pragma unroll
                        for (int r = 0; r < 4; ++r)
                            __hip_atomic_store(hwU + p2 * 4096 + (rowloc + r) * 256,
                                               pk[p2][r], __ATOMIC_RELAXED,
                                               __HIP_MEMORY_SCOPE_AGENT);
                }
            }
        }

        // ---- row-group barrier: per-WG epoch flags ----
        ++stage;
        __syncthreads();    // B2: all waves' reads done; wave0's h stores issued
        if (tid == 0)       // RELEASE: h stores globally visible before flag
            __hip_atomic_store(myflag, stage, __ATOMIC_RELEASE, __HIP_MEMORY_SCOPE_AGENT);

        // deferred work (off the inter-WG critical path, overlaps others' polls):
        if (llast && wv == 0 && isH) {
#pragma unroll
            for (int r = 0; r < 4; ++r) {
                out[(long long)(t * 64 + grow + r) * 1024 + pass * 512 + jH] = hn[r];
                if (t == T_STEPS - 1)
                    hidOut[(grow + r) * 1024 + pass * 512 + jH] = hn[r];
            }
        }
        if (llast && wv == 0 && step < 2 * T_STEPS - 1) {   // prefetch P for next step
            const int sn = step + 1;
            const int tn = (sn >= T_STEPS) ? (sn - T_STEPS) : sn;
            const float* Ptn = P + (long long)tn * 65536;
#pragma unroll
            for (int r = 0; r < 4; ++r) pv[r] = Ptn[(grow + r) * 1024 + ccol];
        }

        // ALL waves poll: each wave's 64 lanes watch the rg's 64 flags.
        {
            bool done = false;
            while (!done) {
                unsigned vv = __hip_atomic_load(gflags + (lane << 2),
                                                __ATOMIC_RELAXED, __HIP_MEMORY_SCOPE_AGENT);
                done = (__ballot(vv >= stage) == ~0ull);
                if (!done) __builtin_amdgcn_s_sleep(1);
            }
        }
        // ACQUIRE: no h load may observe pre-flag data (waitcnt + cache inv)
        __builtin_amdgcn_fence(__ATOMIC_ACQUIRE, "agent");
        __builtin_amdgcn_sched_barrier(0);   // pin next-stage loads behind the fence
    };

#pragma unroll 1
    for (int step = 0; step < 2 * T_STEPS; ++step) {
        const int pass = (step >= T_STEPS) ? 1 : 0;
        const int t = step - pass * T_STEPS;
        layer(w[0], rb[0], 1, 0, t, pass, step);
        layer(w[1], rb[1], 0, 0, t, pass, step);
        layer(w[2], rb[2], 0, 0, t, pass, step);
        layer(w[3], rb[3], 0, 0, t, pass, step);
        layer(w[4], rb[4], 0, 1, t, pass, step);
    }
}

extern "C" void kernel_launch(void* const* d_in, const int* in_sizes, int n_in,
                              void* d_out, int out_size, void* d_ws, size_t ws_size,
                              hipStream_t stream)
{
    const float* x   = (const float*)d_in[0];
    const float* WHw = (const float*)d_in[1];
    const float* WHb = (const float*)d_in[2];
    const float* WCw = (const float*)d_in[3];
    const float* WCb = (const float*)d_in[4];
    const float* RHw = (const float*)d_in[5];
    const float* RHb = (const float*)d_in[6];
    const float* RCw = (const float*)d_in[7];
    const float* RCb = (const float*)d_in[8];

    char* ws = (char*)d_ws;
    float*    Pbuf  = (float*)(ws + OFF_P);
    short*    Wt    = (short*)(ws + OFF_W);
    short*    Rt    = (short*)(ws + OFF_R);
    float*    wbc   = (float*)(ws + OFF_WBC);
    float*    rbc   = (float*)(ws + OFF_RBC);
    short*    hbuf  = (short*)(ws + OFF_H);
    unsigned* flags = (unsigned*)(ws + OFF_FLAGS);
    float*    outp  = (float*)d_out;

    rhn_prep<<<15132, 256, 0, stream>>>(WHw, WHb, WCw, WCb, RHw, RHb, RCw, RCb,
                                        Wt, Rt, wbc, rbc, hbuf, flags);
    rhn_proj<<<dim3(16, 512), 256, 0, stream>>>(x, Wt, wbc, Pbuf);

    rhn_rec<<<dim3(256), dim3(256), 0, stream>>>(Pbuf, Rt, rbc, hbuf, flags, outp);
}